// Round 2
// baseline (548.815 us; speedup 1.0000x reference)
//
#include <hip/hip_runtime.h>
#include <math.h>

// Problem constants
#define HH   1024
#define SS   5
#define LL   4
#define INW  42
#define CC   500

// ws layout (float offsets)
#define WS_XS     0      // 210 floats
#define WS_HA     256    // 5120 floats
#define WS_HB     5632   // 5120 floats
#define WS_FUSED  11008  // 1024 floats

__device__ __forceinline__ float sigf(float v) { return 1.0f / (1.0f + expf(-v)); }

__device__ __forceinline__ float wave_sum(float v) {
#pragma unroll
    for (int m = 32; m >= 1; m >>= 1) v += __shfl_xor(v, m, 64);
    return v;
}

// ---------------------------------------------------------------------------
// 1) _prepare: x (1,133,2) -> xs (5,42) = 210 floats
// ---------------------------------------------------------------------------
__global__ void prep_kernel(const float* __restrict__ x, float* __restrict__ xs) {
    int t = threadIdx.x;
    const float sbx = x[0 * 2 + 0],   sby = x[0 * 2 + 1];
    const float slx = x[100 * 2 + 0], sly = x[100 * 2 + 1];
    const float srx = x[121 * 2 + 0], sry = x[121 * 2 + 1];

    float lminx = 1e30f, lmaxx = -1e30f, lminy = 1e30f, lmaxy = -1e30f;
    float rminx = 1e30f, rmaxx = -1e30f, rminy = 1e30f, rmaxy = -1e30f;
    for (int i = 0; i < 21; ++i) {
        float lx = x[(91 + i) * 2 + 0], ly = x[(91 + i) * 2 + 1];
        float rx = x[(112 + i) * 2 + 0], ry = x[(112 + i) * 2 + 1];
        lminx = fminf(lminx, lx); lmaxx = fmaxf(lmaxx, lx);
        lminy = fminf(lminy, ly); lmaxy = fmaxf(lmaxy, ly);
        rminx = fminf(rminx, rx); rmaxx = fmaxf(rmaxx, rx);
        rminy = fminf(rminy, ry); rmaxy = fmaxf(rmaxy, ry);
    }
    float w_l = lmaxx - lminx, h_l = lmaxy - lminy;
    float w_r = rmaxx - rminx, h_r = rmaxy - rminy;
    float w_b = x[5 * 2 + 0] - x[6 * 2 + 0];
    float h_b = 4.0f * w_b;

    bool cl = (w_l != 0.0f) && (h_l != 0.0f);
    float dlx = cl ? w_l : 1.0f, dly = cl ? h_l : 1.0f;
    bool cr = (w_r != 0.0f) && (h_r != 0.0f);
    float drx = cr ? w_r : 1.0f, dry = cr ? h_r : 1.0f;
    bool cb = (w_b != 0.0f) && (h_b != 0.0f);
    float wb = cb ? w_b : 1.0f, hb = cb ? h_b : 1.0f;

    if (t < 105) {
        int grp = t / 21, i = t % 21;
        float lx = x[(91 + i) * 2 + 0], ly = x[(91 + i) * 2 + 1];
        float rx = x[(112 + i) * 2 + 0], ry = x[(112 + i) * 2 + 1];
        float ox = 0.0f, oy = 0.0f;
        switch (grp) {
            case 0: ox = (lx - slx) / dlx; oy = (ly - sly) / dly; break;  // left
            case 1: ox = (rx - srx) / drx; oy = (ry - sry) / dry; break;  // right
            case 2: ox = (lx - sbx) / wb;  oy = (ly - sby);       break;  // f2l / [wb,1]
            case 3: ox = (rx - sbx);       oy = (ry - sby) / hb;  break;  // f2r / [1,hb]
            case 4: ox = (lx - rx) / wb;   oy = (ly - ry) / hb;   break;  // h2h / [wb,hb]
        }
        xs[t * 2 + 0] = ox;
        xs[t * 2 + 1] = oy;
    }
}

// ---------------------------------------------------------------------------
// 2) Layer 0: gates = W_ih0[s] @ xs[s] + b ; h = sig(o)*tanh(sig(i)*tanh(g))
//    One wave per (s, j) output. f-gate rows and W_hh@0 skipped (h0==c0==0).
// ---------------------------------------------------------------------------
__global__ __launch_bounds__(256) void layer0_kernel(
    const float* __restrict__ W,     // (S, 4H, INW)
    const float* __restrict__ b_ih,  // (S, L, 4H)
    const float* __restrict__ b_hh,  // (S, L, 4H)
    const float* __restrict__ xs,    // (S, INW)
    float* __restrict__ hout)        // (S, H)
{
    int wid = (blockIdx.x << 2) + (threadIdx.x >> 6);
    int lane = threadIdx.x & 63;
    int s = wid >> 10, j = wid & 1023;

    const float* Ws = W + (size_t)s * 4096 * INW;
    float ai = 0.0f, ag = 0.0f, ao = 0.0f;
    if (lane < INW) {
        float xv = xs[s * INW + lane];
        ai = Ws[(size_t)(j) * INW + lane] * xv;
        ag = Ws[(size_t)(2048 + j) * INW + lane] * xv;
        ao = Ws[(size_t)(3072 + j) * INW + lane] * xv;
    }
    ai = wave_sum(ai); ag = wave_sum(ag); ao = wave_sum(ao);

    if (lane == 0) {
        const float* bi = b_ih + (size_t)(s * LL + 0) * 4096;
        const float* bh = b_hh + (size_t)(s * LL + 0) * 4096;
        float gi = ai + bi[j] + bh[j];
        float gg = ag + bi[2048 + j] + bh[2048 + j];
        float go = ao + bi[3072 + j] + bh[3072 + j];
        float c = sigf(gi) * tanhf(gg);
        hout[s * HH + j] = sigf(go) * tanhf(c);
    }
}

// ---------------------------------------------------------------------------
// 3) Layers 1..3: gates = W_ihr[s,layer-1] @ h[s] + b ; same activation.
//    One wave per (s, j); 3 live rows x 1024 via float4, fully unrolled.
// ---------------------------------------------------------------------------
__global__ __launch_bounds__(256) void layer_kernel(
    const float* __restrict__ W,     // (S, L-1, 4H, H)
    const float* __restrict__ b_ih,
    const float* __restrict__ b_hh,
    int layer,                       // 1..3
    const float* __restrict__ hin,   // (S, H)
    float* __restrict__ hout)        // (S, H)
{
    int wid = (blockIdx.x << 2) + (threadIdx.x >> 6);
    int lane = threadIdx.x & 63;
    int s = wid >> 10, j = wid & 1023;

    const float* Ws = W + (size_t)(s * (LL - 1) + (layer - 1)) * 4096 * HH;
    const float4* ri = (const float4*)(Ws + (size_t)(j) * HH);
    const float4* rg = (const float4*)(Ws + (size_t)(2048 + j) * HH);
    const float4* ro = (const float4*)(Ws + (size_t)(3072 + j) * HH);
    const float4* hv = (const float4*)(hin + s * HH);

    float ai = 0.0f, ag = 0.0f, ao = 0.0f;
#pragma unroll
    for (int k = 0; k < 4; ++k) {
        int idx = (k << 6) + lane;
        float4 h4 = hv[idx];
        float4 wi = ri[idx];
        float4 wg = rg[idx];
        float4 wo = ro[idx];
        ai += wi.x * h4.x + wi.y * h4.y + wi.z * h4.z + wi.w * h4.w;
        ag += wg.x * h4.x + wg.y * h4.y + wg.z * h4.z + wg.w * h4.w;
        ao += wo.x * h4.x + wo.y * h4.y + wo.z * h4.z + wo.w * h4.w;
    }
    ai = wave_sum(ai); ag = wave_sum(ag); ao = wave_sum(ao);

    if (lane == 0) {
        const float* bi = b_ih + (size_t)(s * LL + layer) * 4096;
        const float* bh = b_hh + (size_t)(s * LL + layer) * 4096;
        float gi = ai + bi[j] + bh[j];
        float gg = ag + bi[2048 + j] + bh[2048 + j];
        float go = ao + bi[3072 + j] + bh[3072 + j];
        float c = sigf(gi) * tanhf(gg);
        hout[s * HH + j] = sigf(go) * tanhf(c);
    }
}

// ---------------------------------------------------------------------------
// 4) fuse: fused[j] = dot(fuse_w[j,:], hflat[0:5120]) + fuse_b[j]
//    (attention after this is a provable no-op: softmax over length-1 axis)
// ---------------------------------------------------------------------------
__global__ __launch_bounds__(256) void fuse_kernel(
    const float* __restrict__ fw,    // (H, S*H)
    const float* __restrict__ fb,    // (H)
    const float* __restrict__ hflat, // (S*H)
    float* __restrict__ fused)       // (H)
{
    int wid = (blockIdx.x << 2) + (threadIdx.x >> 6);
    int lane = threadIdx.x & 63;
    int j = wid;

    const float4* row = (const float4*)(fw + (size_t)j * (SS * HH));
    const float4* hv = (const float4*)hflat;
    float a = 0.0f;
#pragma unroll
    for (int k = 0; k < 20; ++k) {
        int idx = (k << 6) + lane;
        float4 w = row[idx];
        float4 h = hv[idx];
        a += w.x * h.x + w.y * h.y + w.z * h.z + w.w * h.w;
    }
    a = wave_sum(a);
    if (lane == 0) fused[j] = a + fb[j];
}

// ---------------------------------------------------------------------------
// 5) fc: out[c] = dot(fc_w[c,:], fused) + fc_b[c]
// ---------------------------------------------------------------------------
__global__ __launch_bounds__(256) void fc_kernel(
    const float* __restrict__ fw,    // (C, H)
    const float* __restrict__ fb,    // (C)
    const float* __restrict__ fused, // (H)
    float* __restrict__ out)         // (C)
{
    int wid = (blockIdx.x << 2) + (threadIdx.x >> 6);
    int lane = threadIdx.x & 63;
    int c = wid;
    if (c >= CC) return;

    const float4* row = (const float4*)(fw + (size_t)c * HH);
    const float4* hv = (const float4*)fused;
    float a = 0.0f;
#pragma unroll
    for (int k = 0; k < 4; ++k) {
        int idx = (k << 6) + lane;
        float4 w = row[idx];
        float4 h = hv[idx];
        a += w.x * h.x + w.y * h.y + w.z * h.z + w.w * h.w;
    }
    a = wave_sum(a);
    if (lane == 0) out[c] = a + fb[c];
}

extern "C" void kernel_launch(void* const* d_in, const int* in_sizes, int n_in,
                              void* d_out, int out_size, void* d_ws, size_t ws_size,
                              hipStream_t stream) {
    const float* x      = (const float*)d_in[0];
    const float* W_ih0  = (const float*)d_in[1];
    const float* W_ihr  = (const float*)d_in[2];
    // d_in[3] = W_hh : multiplied by h0 == 0, never read
    const float* b_ih   = (const float*)d_in[4];
    const float* b_hh   = (const float*)d_in[5];
    const float* fuse_w = (const float*)d_in[6];
    const float* fuse_b = (const float*)d_in[7];
    // d_in[8..11] = att_w, att_b, score_w, score_b : softmax over length-1 axis => no-op
    const float* fc_w   = (const float*)d_in[12];
    const float* fc_b   = (const float*)d_in[13];
    float* out = (float*)d_out;

    float* ws    = (float*)d_ws;
    float* xs    = ws + WS_XS;
    float* hA    = ws + WS_HA;
    float* hB    = ws + WS_HB;
    float* fused = ws + WS_FUSED;

    prep_kernel<<<1, 128, 0, stream>>>(x, xs);
    layer0_kernel<<<1280, 256, 0, stream>>>(W_ih0, b_ih, b_hh, xs, hA);
    layer_kernel<<<1280, 256, 0, stream>>>(W_ihr, b_ih, b_hh, 1, hA, hB);
    layer_kernel<<<1280, 256, 0, stream>>>(W_ihr, b_ih, b_hh, 2, hB, hA);
    layer_kernel<<<1280, 256, 0, stream>>>(W_ihr, b_ih, b_hh, 3, hA, hB);
    fuse_kernel<<<256, 256, 0, stream>>>(fuse_w, fuse_b, hB, fused);
    fc_kernel<<<125, 256, 0, stream>>>(fc_w, fc_b, fused, out);
}